// Round 1
// baseline (3758.517 us; speedup 1.0000x reference)
//
#include <hip/hip_runtime.h>
#include <stdint.h>

#define VOCAB 32000
#define EMBD 512
#define HID 512
#define BATCH 32
#define SEQL 512

typedef short bf16x8 __attribute__((ext_vector_type(8)));
typedef short bf16x4 __attribute__((ext_vector_type(4)));
typedef float f32x4 __attribute__((ext_vector_type(4)));

static __device__ __forceinline__ float bf2f(short u) {
  union { unsigned u; float f; } c;
  c.u = ((unsigned)(unsigned short)u) << 16;
  return c.f;
}
static __device__ __forceinline__ unsigned short f2bf(float f) {
  union { float f; unsigned u; } c;
  c.f = f;
  unsigned x = c.u;
  unsigned r = (x + 0x7fffu + ((x >> 16) & 1u)) >> 16;
  return (unsigned short)r;
}

// ---------------- f32 -> bf16 convert (8 elems/thread) ----------------
__global__ __launch_bounds__(256) void cvt_f32_bf16(
    const float* __restrict__ src, unsigned short* __restrict__ dst, int n8) {
  int i = blockIdx.x * 256 + threadIdx.x;
  if (i >= n8) return;
  const float4* s = (const float4*)src + (size_t)i * 2;
  float4 a = s[0], b = s[1];
  uint4 p;
  p.x = (unsigned)f2bf(a.x) | ((unsigned)f2bf(a.y) << 16);
  p.y = (unsigned)f2bf(a.z) | ((unsigned)f2bf(a.w) << 16);
  p.z = (unsigned)f2bf(b.x) | ((unsigned)f2bf(b.y) << 16);
  p.w = (unsigned)f2bf(b.z) | ((unsigned)f2bf(b.w) << 16);
  ((uint4*)dst)[i] = p;
}

// ---------------- gx GEMM: gx[s][d][g][b] = x[b,s,:]·W_ih[d,g,:] + b_ih ----
// A rows: m = s*32 + b (gathered from emb via token). B rows: n = d*1536+g.
#define GBM 128
#define GBN 128
#define GBK 64

__global__ __launch_bounds__(256) void gemm_gx(
    const int* __restrict__ enc,                 // [B][S]
    const unsigned short* __restrict__ embb,     // [VOCAB][512] bf16
    const unsigned short* __restrict__ wih,      // [3072][512] bf16
    const float* __restrict__ b_ih,              // [3072]
    unsigned short* __restrict__ gx)             // [S][2][1536][32] bf16
{
  __shared__ __align__(16) unsigned short As[GBM * GBK];
  __shared__ __align__(16) unsigned short Bs[GBN * GBK];
  __shared__ int tokl[GBM];

  const int n0 = blockIdx.x * GBN;   // x = n so concurrent blocks share A in L2
  const int m0 = blockIdx.y * GBM;
  const int tid = threadIdx.x;
  if (tid < GBM) {
    int m = m0 + tid;
    tokl[tid] = enc[(m & 31) * SEQL + (m >> 5)];
  }
  __syncthreads();

  const int l = tid & 63, w = tid >> 6;
  const int wr = w >> 1, wc = w & 1;

  f32x4 acc[4][4];
  f32x4 zero = {0.f, 0.f, 0.f, 0.f};
#pragma unroll
  for (int mt = 0; mt < 4; ++mt)
#pragma unroll
    for (int nt = 0; nt < 4; ++nt) acc[mt][nt] = zero;

  for (int kt = 0; kt < 512; kt += GBK) {
#pragma unroll
    for (int it = 0; it < 4; ++it) {  // A stage: 1024 x 16B chunks
      int c = it * 256 + tid;
      int r = c >> 3, kc = c & 7;
      uint4 v = *(const uint4*)(embb + (size_t)tokl[r] * 512 + kt + kc * 8);
      unsigned off = (unsigned)(r * 128 + kc * 16); off ^= (r & 7) << 4;
      *(uint4*)((char*)As + off) = v;
    }
#pragma unroll
    for (int it = 0; it < 4; ++it) {  // B stage
      int c = it * 256 + tid;
      int r = c >> 3, kc = c & 7;
      uint4 v = *(const uint4*)(wih + (size_t)(n0 + r) * 512 + kt + kc * 8);
      unsigned off = (unsigned)(r * 128 + kc * 16); off ^= (r & 7) << 4;
      *(uint4*)((char*)Bs + off) = v;
    }
    __syncthreads();
#pragma unroll
    for (int ks = 0; ks < 2; ++ks) {
      bf16x8 af[4], bfr[4];
#pragma unroll
      for (int mt = 0; mt < 4; ++mt) {
        int r = wr * 64 + mt * 16 + (l & 15);
        unsigned off = (unsigned)(r * 128 + ks * 64 + (l >> 4) * 16);
        off ^= (r & 7) << 4;
        af[mt] = *(const bf16x8*)((char*)As + off);
      }
#pragma unroll
      for (int nt = 0; nt < 4; ++nt) {
        int r = wc * 64 + nt * 16 + (l & 15);
        unsigned off = (unsigned)(r * 128 + ks * 64 + (l >> 4) * 16);
        off ^= (r & 7) << 4;
        bfr[nt] = *(const bf16x8*)((char*)Bs + off);
      }
#pragma unroll
      for (int mt = 0; mt < 4; ++mt)
#pragma unroll
        for (int nt = 0; nt < 4; ++nt)
          acc[mt][nt] = __builtin_amdgcn_mfma_f32_16x16x32_bf16(
              af[mt], bfr[nt], acc[mt][nt], 0, 0, 0);
    }
    __syncthreads();
  }

  // epilogue: add bias, pack 4 consecutive b as 8B store
#pragma unroll
  for (int nt = 0; nt < 4; ++nt) {
    int n = n0 + wc * 64 + nt * 16 + (l & 15);
    int d = n >= 1536 ? 1 : 0;
    int g = n - d * 1536;
    float bias = b_ih[n];
#pragma unroll
    for (int mt = 0; mt < 4; ++mt) {
      int mbase = m0 + wr * 64 + mt * 16 + (l >> 4) * 4;
      int s = mbase >> 5;
      int b = mbase & 31;
      unsigned v0 = (unsigned)f2bf(acc[mt][nt][0] + bias) |
                    ((unsigned)f2bf(acc[mt][nt][1] + bias) << 16);
      unsigned v1 = (unsigned)f2bf(acc[mt][nt][2] + bias) |
                    ((unsigned)f2bf(acc[mt][nt][3] + bias) << 16);
      size_t off = ((size_t)(s * 2 + d) * 1536 + g) * 32 + b;
      uint2 pv; pv.x = v0; pv.y = v1;
      *(uint2*)(gx + off) = pv;
    }
  }
}

// ---------------- persistent GRU scan -------------------------------------
// 64 WGs = 2 dirs x 32 j-slices (JW=16). 128 threads = 2 waves (b-halves).
// Per-dir monotonic counter barrier per step.
#define JW 16
#define NWGD 32

__global__ __launch_bounds__(128) void scan_gru(
    const unsigned short* __restrict__ gx,    // [S][2][1536][32]
    const unsigned short* __restrict__ whh,   // [2][1536][512] bf16
    const float* __restrict__ bhh,            // [2][1536]
    unsigned short* __restrict__ hbuf,        // [2][2][32][512] bf16
    float* __restrict__ out,                  // encoded + hidden
    unsigned* __restrict__ ctr)               // [2] at stride 32 u32
{
  __shared__ __align__(16) unsigned short Wl[48 * 512];  // 48KB, swizzled

  const int bid = blockIdx.x;
  const int d = bid >> 5;
  const int wg = bid & 31;
  const int j0 = wg * JW;
  const int tid = threadIdx.x;
  const int l = tid & 63;
  const int w = tid >> 6;       // wave = b-half

  // stage W_hh slice: rows lr = gate*16 + jj  ->  global row gate*512+j0+jj
  for (int it = 0; it < 24; ++it) {
    int c = it * 128 + tid;      // 16B chunks; 64 per row
    int lr = c >> 6, kc = c & 63;
    int gate = lr >> 4, jj = lr & 15;
    uint4 v = *(const uint4*)(whh +
        (size_t)(d * 1536 + gate * 512 + j0 + jj) * 512 + kc * 8);
    unsigned off = (unsigned)(lr * 1024 + kc * 16); off ^= (lr & 7) << 4;
    *(uint4*)((char*)Wl + off) = v;
  }

  const int jl = l & 15;
  const int jglob = j0 + jl;
  const int b0 = w * 16;
  const int brow = b0 + (l >> 4) * 4;   // first of 4 C-rows (batch) this lane owns
  const float bh_r = bhh[d * 1536 + jglob];
  const float bh_z = bhh[d * 1536 + 512 + jglob];
  const float bh_n = bhh[d * 1536 + 1024 + jglob];

  float hold[4] = {0.f, 0.f, 0.f, 0.f};
  unsigned* myctr = ctr + d * 32;

  __syncthreads();  // Wl ready

  for (int t = 0; t < SEQL; ++t) {
    // gx for this step (bias b_ih already folded in)
    size_t gbase = ((size_t)t * 2 + d) * 1536 * 32;
    bf16x4 gr = *(const bf16x4*)(gx + gbase + (size_t)jglob * 32 + brow);
    bf16x4 gz = *(const bf16x4*)(gx + gbase + (size_t)(512 + jglob) * 32 + brow);
    bf16x4 gn = *(const bf16x4*)(gx + gbase + (size_t)(1024 + jglob) * 32 + brow);

    f32x4 accr = {0.f, 0.f, 0.f, 0.f};
    f32x4 accz = accr, accn = accr;

    if (t > 0) {
      const unsigned short* hp =
          hbuf + (size_t)(d * 2 + ((t - 1) & 1)) * 32 * 512;
      const unsigned short* hrow = hp + (size_t)(b0 + (l & 15)) * 512 + (l >> 4) * 8;
      bf16x8 af[16];
#pragma unroll
      for (int ks = 0; ks < 16; ++ks)
        af[ks] = *(const bf16x8*)(hrow + ks * 32);
#pragma unroll
      for (int ks = 0; ks < 16; ++ks) {
        unsigned kb = (unsigned)(ks * 64 + (l >> 4) * 16);
        unsigned r0 = (unsigned)jl, r1 = (unsigned)(16 + jl), r2 = (unsigned)(32 + jl);
        bf16x8 bR = *(const bf16x8*)((char*)Wl + ((r0 * 1024 + kb) ^ ((r0 & 7) << 4)));
        bf16x8 bZ = *(const bf16x8*)((char*)Wl + ((r1 * 1024 + kb) ^ ((r1 & 7) << 4)));
        bf16x8 bN = *(const bf16x8*)((char*)Wl + ((r2 * 1024 + kb) ^ ((r2 & 7) << 4)));
        accr = __builtin_amdgcn_mfma_f32_16x16x32_bf16(af[ks], bR, accr, 0, 0, 0);
        accz = __builtin_amdgcn_mfma_f32_16x16x32_bf16(af[ks], bZ, accz, 0, 0, 0);
        accn = __builtin_amdgcn_mfma_f32_16x16x32_bf16(af[ks], bN, accn, 0, 0, 0);
      }
    }

    unsigned short* hn = hbuf + (size_t)(d * 2 + (t & 1)) * 32 * 512;
#pragma unroll
    for (int i = 0; i < 4; ++i) {
      float ghr = accr[i] + bh_r;
      float ghz = accz[i] + bh_z;
      float ghn = accn[i] + bh_n;
      float pr = bf2f(gr[i]) + ghr;
      float pz = bf2f(gz[i]) + ghz;
      float r = 1.f / (1.f + __expf(-pr));
      float z = 1.f / (1.f + __expf(-pz));
      float n = tanhf(bf2f(gn[i]) + r * ghn);
      float h = (1.f - z) * n + z * hold[i];
      hold[i] = h;
      hn[(size_t)(brow + i) * 512 + jglob] = f2bf(h);
      out[((size_t)(brow + i) * SEQL + t) * 1024 + d * 512 + jglob] = h;
    }
    if (t == SEQL - 1) {
#pragma unroll
      for (int i = 0; i < 4; ++i)
        out[(size_t)BATCH * SEQL * 1024 +
            (size_t)(d * 32 + brow + i) * 512 + jglob] = hold[i];
    }

    if (t < SEQL - 1) {
      __syncthreads();
      if (tid == 0) {
        __threadfence();  // release: make h stores agent-visible
        __hip_atomic_fetch_add(myctr, 1u, __ATOMIC_RELAXED,
                               __HIP_MEMORY_SCOPE_AGENT);
        unsigned tgt = (unsigned)(t + 1) * NWGD;
        while (__hip_atomic_load(myctr, __ATOMIC_RELAXED,
                                 __HIP_MEMORY_SCOPE_AGENT) < tgt)
          __builtin_amdgcn_s_sleep(2);
        __threadfence();  // acquire
      }
      __syncthreads();
    }
  }
}

extern "C" void kernel_launch(void* const* d_in, const int* in_sizes, int n_in,
                              void* d_out, int out_size, void* d_ws, size_t ws_size,
                              hipStream_t stream) {
  const int* enc = (const int*)d_in[0];
  const float* emb = (const float*)d_in[1];
  const float* wih = (const float*)d_in[2];
  const float* whh = (const float*)d_in[3];
  const float* bih = (const float*)d_in[4];
  const float* bhh = (const float*)d_in[5];
  float* out = (float*)d_out;

  char* ws = (char*)d_ws;
  // layout (all 16B-aligned):
  //   [0,256)        barrier counters
  //   +256           hbuf  2*2*32*512*2      = 131072
  //   +131328        whh_b 2*1536*512*2      = 3145728
  //   +3277056+256.. wih_b 3145728
  //   emb_b 32768000, gx 100663296
  unsigned* ctr = (unsigned*)ws;
  unsigned short* hbuf = (unsigned short*)(ws + 256);
  unsigned short* whh_b = (unsigned short*)(ws + 256 + 131072);
  unsigned short* wih_b = (unsigned short*)(ws + 256 + 131072 + 3145728);
  unsigned short* emb_b = (unsigned short*)(ws + 256 + 131072 + 2 * 3145728);
  unsigned short* gx = (unsigned short*)(ws + 256 + 131072 + 2 * 3145728 + 32768000);

  hipMemsetAsync(ctr, 0, 256, stream);
  cvt_f32_bf16<<<768, 256, 0, stream>>>(whh, whh_b, 196608);
  cvt_f32_bf16<<<768, 256, 0, stream>>>(wih, wih_b, 196608);
  cvt_f32_bf16<<<8000, 256, 0, stream>>>(emb, emb_b, 2048000);
  gemm_gx<<<dim3(24, 128), 256, 0, stream>>>(enc, emb_b, wih_b, bih, gx);
  scan_gru<<<64, 128, 0, stream>>>(gx, whh_b, bhh, hbuf, out, ctr);
}

// Round 2
// 2101.747 us; speedup vs baseline: 1.7883x; 1.7883x over previous
//
#include <hip/hip_runtime.h>
#include <stdint.h>

#define VOCAB 32000
#define EMBD 512
#define HID 512
#define BATCH 32
#define SEQL 512

typedef short bf16x8 __attribute__((ext_vector_type(8)));
typedef short bf16x4 __attribute__((ext_vector_type(4)));
typedef float f32x4 __attribute__((ext_vector_type(4)));

static __device__ __forceinline__ float bf2f(short u) {
  union { unsigned u; float f; } c;
  c.u = ((unsigned)(unsigned short)u) << 16;
  return c.f;
}
static __device__ __forceinline__ unsigned short f2bf(float f) {
  union { float f; unsigned u; } c;
  c.f = f;
  unsigned x = c.u;
  unsigned r = (x + 0x7fffu + ((x >> 16) & 1u)) >> 16;
  return (unsigned short)r;
}

// ---------------- f32 -> bf16 convert (8 elems/thread) ----------------
__global__ __launch_bounds__(256) void cvt_f32_bf16(
    const float* __restrict__ src, unsigned short* __restrict__ dst, int n8) {
  int i = blockIdx.x * 256 + threadIdx.x;
  if (i >= n8) return;
  const float4* s = (const float4*)src + (size_t)i * 2;
  float4 a = s[0], b = s[1];
  uint4 p;
  p.x = (unsigned)f2bf(a.x) | ((unsigned)f2bf(a.y) << 16);
  p.y = (unsigned)f2bf(a.z) | ((unsigned)f2bf(a.w) << 16);
  p.z = (unsigned)f2bf(b.x) | ((unsigned)f2bf(b.y) << 16);
  p.w = (unsigned)f2bf(b.z) | ((unsigned)f2bf(b.w) << 16);
  ((uint4*)dst)[i] = p;
}

// ---------------- gx GEMM: gx[s][d][g][b] = x[b,s,:]·W_ih[d,g,:] + b_ih ----
#define GBM 128
#define GBN 128
#define GBK 64

__global__ __launch_bounds__(256) void gemm_gx(
    const int* __restrict__ enc,                 // [B][S]
    const unsigned short* __restrict__ embb,     // [VOCAB][512] bf16
    const unsigned short* __restrict__ wih,      // [3072][512] bf16
    const float* __restrict__ b_ih,              // [3072]
    unsigned short* __restrict__ gx)             // [S][2][1536][32] bf16
{
  __shared__ __align__(16) unsigned short As[GBM * GBK];
  __shared__ __align__(16) unsigned short Bs[GBN * GBK];
  __shared__ int tokl[GBM];

  const int n0 = blockIdx.x * GBN;
  const int m0 = blockIdx.y * GBM;
  const int tid = threadIdx.x;
  if (tid < GBM) {
    int m = m0 + tid;
    tokl[tid] = enc[(m & 31) * SEQL + (m >> 5)];
  }
  __syncthreads();

  const int l = tid & 63, w = tid >> 6;
  const int wr = w >> 1, wc = w & 1;

  f32x4 acc[4][4];
  f32x4 zero = {0.f, 0.f, 0.f, 0.f};
#pragma unroll
  for (int mt = 0; mt < 4; ++mt)
#pragma unroll
    for (int nt = 0; nt < 4; ++nt) acc[mt][nt] = zero;

  for (int kt = 0; kt < 512; kt += GBK) {
#pragma unroll
    for (int it = 0; it < 4; ++it) {  // A stage
      int c = it * 256 + tid;
      int r = c >> 3, kc = c & 7;
      uint4 v = *(const uint4*)(embb + (size_t)tokl[r] * 512 + kt + kc * 8);
      unsigned off = (unsigned)(r * 128 + kc * 16); off ^= (r & 7) << 4;
      *(uint4*)((char*)As + off) = v;
    }
#pragma unroll
    for (int it = 0; it < 4; ++it) {  // B stage
      int c = it * 256 + tid;
      int r = c >> 3, kc = c & 7;
      uint4 v = *(const uint4*)(wih + (size_t)(n0 + r) * 512 + kt + kc * 8);
      unsigned off = (unsigned)(r * 128 + kc * 16); off ^= (r & 7) << 4;
      *(uint4*)((char*)Bs + off) = v;
    }
    __syncthreads();
#pragma unroll
    for (int ks = 0; ks < 2; ++ks) {
      bf16x8 af[4], bfr[4];
#pragma unroll
      for (int mt = 0; mt < 4; ++mt) {
        int r = wr * 64 + mt * 16 + (l & 15);
        unsigned off = (unsigned)(r * 128 + ks * 64 + (l >> 4) * 16);
        off ^= (r & 7) << 4;
        af[mt] = *(const bf16x8*)((char*)As + off);
      }
#pragma unroll
      for (int nt = 0; nt < 4; ++nt) {
        int r = wc * 64 + nt * 16 + (l & 15);
        unsigned off = (unsigned)(r * 128 + ks * 64 + (l >> 4) * 16);
        off ^= (r & 7) << 4;
        bfr[nt] = *(const bf16x8*)((char*)Bs + off);
      }
#pragma unroll
      for (int mt = 0; mt < 4; ++mt)
#pragma unroll
        for (int nt = 0; nt < 4; ++nt)
          acc[mt][nt] = __builtin_amdgcn_mfma_f32_16x16x32_bf16(
              af[mt], bfr[nt], acc[mt][nt], 0, 0, 0);
    }
    __syncthreads();
  }

#pragma unroll
  for (int nt = 0; nt < 4; ++nt) {
    int n = n0 + wc * 64 + nt * 16 + (l & 15);
    int d = n >= 1536 ? 1 : 0;
    int g = n - d * 1536;
    float bias = b_ih[n];
#pragma unroll
    for (int mt = 0; mt < 4; ++mt) {
      int mbase = m0 + wr * 64 + mt * 16 + (l >> 4) * 4;
      int s = mbase >> 5;
      int b = mbase & 31;
      unsigned v0 = (unsigned)f2bf(acc[mt][nt][0] + bias) |
                    ((unsigned)f2bf(acc[mt][nt][1] + bias) << 16);
      unsigned v1 = (unsigned)f2bf(acc[mt][nt][2] + bias) |
                    ((unsigned)f2bf(acc[mt][nt][3] + bias) << 16);
      size_t off = ((size_t)(s * 2 + d) * 1536 + g) * 32 + b;
      uint2 pv; pv.x = v0; pv.y = v1;
      *(uint2*)(gx + off) = pv;
    }
  }
}

// ---------------- persistent GRU scan -------------------------------------
// 64 WGs = 2 dirs x 32 j-slices (JW=16). 128 threads = 2 waves (b-halves).
// All cross-WG traffic via relaxed AGENT-scope atomics (sc1, MALL-coherent);
// no threadfence. Per-WG flag on its own 64B line, parallel poll + ballot.
#define JW 16
#define NWGD 32

__global__ __launch_bounds__(128) void scan_gru(
    const unsigned short* __restrict__ gx,    // [S][2][1536][32]
    const unsigned short* __restrict__ whh,   // [2][1536][512] bf16
    const float* __restrict__ bhh,            // [2][1536]
    unsigned short* __restrict__ hbuf,        // [2][2][32][512] bf16
    float* __restrict__ out,                  // encoded + hidden
    unsigned* __restrict__ flags)             // [2][32] u32, 64B stride
{
  __shared__ __align__(16) unsigned short Wl[48 * 512];  // 48KB, swizzled

  const int bid = blockIdx.x;
  const int d = bid >> 5;
  const int wg = bid & 31;
  const int j0 = wg * JW;
  const int tid = threadIdx.x;
  const int l = tid & 63;
  const int w = tid >> 6;       // wave = b-half

  // stage W_hh slice: rows lr = gate*16 + jj  ->  global row gate*512+j0+jj
  for (int it = 0; it < 24; ++it) {
    int c = it * 128 + tid;      // 16B chunks; 64 per row
    int lr = c >> 6, kc = c & 63;
    int gate = lr >> 4, jj = lr & 15;
    uint4 v = *(const uint4*)(whh +
        (size_t)(d * 1536 + gate * 512 + j0 + jj) * 512 + kc * 8);
    unsigned off = (unsigned)(lr * 1024 + kc * 16); off ^= (lr & 7) << 4;
    *(uint4*)((char*)Wl + off) = v;
  }

  const int jl = l & 15;
  const int jglob = j0 + jl;
  const int b0 = w * 16;
  const int brow = b0 + (l >> 4) * 4;   // first of 4 C-rows (batch) this lane owns
  const float bh_r = bhh[d * 1536 + jglob];
  const float bh_z = bhh[d * 1536 + 512 + jglob];
  const float bh_n = bhh[d * 1536 + 1024 + jglob];

  float hold[4] = {0.f, 0.f, 0.f, 0.f};
  unsigned* myflag = flags + (size_t)(d * 32 + wg) * 16;  // own 64B line
  const unsigned* fbase = flags + (size_t)d * 32 * 16;

  __syncthreads();  // Wl ready

  // prefetch gx for t=0
  bf16x4 gr, gz, gn;
  {
    size_t gb = (size_t)d * 1536 * 32;
    gr = *(const bf16x4*)(gx + gb + (size_t)jglob * 32 + brow);
    gz = *(const bf16x4*)(gx + gb + (size_t)(512 + jglob) * 32 + brow);
    gn = *(const bf16x4*)(gx + gb + (size_t)(1024 + jglob) * 32 + brow);
  }

  for (int t = 0; t < SEQL; ++t) {
    f32x4 accr = {0.f, 0.f, 0.f, 0.f};
    f32x4 accz = accr, accn = accr;

    if (t > 0) {
      const unsigned long long* hq = (const unsigned long long*)
          (hbuf + (size_t)(d * 2 + ((t - 1) & 1)) * 32 * 512);
      size_t qb = (size_t)(b0 + (l & 15)) * 128 + (l >> 4) * 2;  // u64 units
      union { unsigned long long q[2]; bf16x8 v; } afu[16];
#pragma unroll
      for (int ks = 0; ks < 16; ++ks) {
        afu[ks].q[0] = __hip_atomic_load(hq + qb + ks * 8,
                                         __ATOMIC_RELAXED, __HIP_MEMORY_SCOPE_AGENT);
        afu[ks].q[1] = __hip_atomic_load(hq + qb + ks * 8 + 1,
                                         __ATOMIC_RELAXED, __HIP_MEMORY_SCOPE_AGENT);
      }
#pragma unroll
      for (int ks = 0; ks < 16; ++ks) {
        unsigned kb = (unsigned)(ks * 64 + (l >> 4) * 16);
        unsigned r0 = (unsigned)jl, r1 = (unsigned)(16 + jl), r2 = (unsigned)(32 + jl);
        bf16x8 bR = *(const bf16x8*)((char*)Wl + ((r0 * 1024 + kb) ^ ((r0 & 7) << 4)));
        bf16x8 bZ = *(const bf16x8*)((char*)Wl + ((r1 * 1024 + kb) ^ ((r1 & 7) << 4)));
        bf16x8 bN = *(const bf16x8*)((char*)Wl + ((r2 * 1024 + kb) ^ ((r2 & 7) << 4)));
        accr = __builtin_amdgcn_mfma_f32_16x16x32_bf16(afu[ks].v, bR, accr, 0, 0, 0);
        accz = __builtin_amdgcn_mfma_f32_16x16x32_bf16(afu[ks].v, bZ, accz, 0, 0, 0);
        accn = __builtin_amdgcn_mfma_f32_16x16x32_bf16(afu[ks].v, bN, accn, 0, 0, 0);
      }
    }

    float hv[4];
#pragma unroll
    for (int i = 0; i < 4; ++i) {
      float ghr = accr[i] + bh_r;
      float ghz = accz[i] + bh_z;
      float ghn = accn[i] + bh_n;
      float pr = bf2f(gr[i]) + ghr;
      float pz = bf2f(gz[i]) + ghz;
      float r = 1.f / (1.f + __expf(-pr));
      float z = 1.f / (1.f + __expf(-pz));
      float n = tanhf(bf2f(gn[i]) + r * ghn);
      float h = (1.f - z) * n + z * hold[i];
      hold[i] = h;
      hv[i] = h;
      out[((size_t)(brow + i) * SEQL + t) * 1024 + d * 512 + jglob] = h;
    }
    if (t == SEQL - 1) {
#pragma unroll
      for (int i = 0; i < 4; ++i)
        out[(size_t)BATCH * SEQL * 1024 +
            (size_t)(d * 32 + brow + i) * 512 + jglob] = hold[i];
    }

    if (t < SEQL - 1) {
      // publish h: pack neighbor-lane pair -> 2 aligned u32 agent atomics/lane
      unsigned* hn32 = (unsigned*)(hbuf + (size_t)(d * 2 + (t & 1)) * 32 * 512);
      unsigned mybf[4], pare[4];
#pragma unroll
      for (int i = 0; i < 4; ++i) mybf[i] = f2bf(hv[i]);
#pragma unroll
      for (int i = 0; i < 4; ++i) {
        unsigned ot = (unsigned)__shfl_xor((int)mybf[i], 1);
        pare[i] = (jl & 1) ? (ot | (mybf[i] << 16)) : (mybf[i] | (ot << 16));
      }
      int jc2 = (j0 + (jl & ~1)) >> 1;  // u32 column index
      int i0 = (jl & 1) ? 2 : 0;
      __hip_atomic_store(hn32 + (size_t)(brow + i0) * 256 + jc2, pare[i0],
                         __ATOMIC_RELAXED, __HIP_MEMORY_SCOPE_AGENT);
      __hip_atomic_store(hn32 + (size_t)(brow + i0 + 1) * 256 + jc2, pare[i0 + 1],
                         __ATOMIC_RELAXED, __HIP_MEMORY_SCOPE_AGENT);

      // prefetch next gx (independent of h) so it drains with the stores
      bf16x4 ngr, ngz, ngn;
      {
        size_t gb = ((size_t)(t + 1) * 2 + d) * 1536 * 32;
        ngr = *(const bf16x4*)(gx + gb + (size_t)jglob * 32 + brow);
        ngz = *(const bf16x4*)(gx + gb + (size_t)(512 + jglob) * 32 + brow);
        ngn = *(const bf16x4*)(gx + gb + (size_t)(1024 + jglob) * 32 + brow);
      }

      __syncthreads();  // drains vmcnt(0): h stores acked at MALL
      if (w == 0) {
        unsigned tgt = (unsigned)(t + 1);
        if (l == 0)
          __hip_atomic_store(myflag, tgt, __ATOMIC_RELAXED, __HIP_MEMORY_SCOPE_AGENT);
        for (;;) {
          unsigned v = tgt;
          if (l < 32)
            v = __hip_atomic_load(fbase + (size_t)l * 16,
                                  __ATOMIC_RELAXED, __HIP_MEMORY_SCOPE_AGENT);
          if (__ballot(v >= tgt) == ~0ull) break;
          __builtin_amdgcn_s_sleep(1);
        }
      }
      __syncthreads();
      gr = ngr; gz = ngz; gn = ngn;
    }
  }
}

extern "C" void kernel_launch(void* const* d_in, const int* in_sizes, int n_in,
                              void* d_out, int out_size, void* d_ws, size_t ws_size,
                              hipStream_t stream) {
  const int* enc = (const int*)d_in[0];
  const float* emb = (const float*)d_in[1];
  const float* wih = (const float*)d_in[2];
  const float* whh = (const float*)d_in[3];
  const float* bih = (const float*)d_in[4];
  const float* bhh = (const float*)d_in[5];
  float* out = (float*)d_out;

  char* ws = (char*)d_ws;
  // layout (16B aligned):
  //   [0,4096)   flags (64 x 64B lines)
  //   +4096      hbuf  2*2*32*512*2 = 131072
  //   then whh_b 3145728, wih_b 3145728, emb_b 32768000, gx 100663296
  unsigned* flags = (unsigned*)ws;
  unsigned short* hbuf = (unsigned short*)(ws + 4096);
  unsigned short* whh_b = (unsigned short*)(ws + 4096 + 131072);
  unsigned short* wih_b = (unsigned short*)(ws + 4096 + 131072 + 3145728);
  unsigned short* emb_b = (unsigned short*)(ws + 4096 + 131072 + 2 * 3145728);
  unsigned short* gx = (unsigned short*)(ws + 4096 + 131072 + 2 * 3145728 + 32768000);

  hipMemsetAsync(flags, 0, 4096, stream);
  cvt_f32_bf16<<<768, 256, 0, stream>>>(whh, whh_b, 196608);
  cvt_f32_bf16<<<768, 256, 0, stream>>>(wih, wih_b, 196608);
  cvt_f32_bf16<<<8000, 256, 0, stream>>>(emb, emb_b, 2048000);
  gemm_gx<<<dim3(24, 128), 256, 0, stream>>>(enc, emb_b, wih_b, bih, gx);
  scan_gru<<<64, 128, 0, stream>>>(gx, whh_b, bhh, hbuf, out, flags);
}